// Round 7
// baseline (421.173 us; speedup 1.0000x reference)
//
#include <hip/hip_runtime.h>
#include <hip/hip_fp16.h>

// tensor  [B=512, T=64, N=512] f32 ; W_shared[R=64, N=512, R=64] f32
// W_last  [C=100, R=64, M=64, R=64] f32 ; out [C=100, B=512] f32
//
// v_b (len 64): v <- v @ M_b(t),  M_b(t)[i,k] = sum_j x[b,t,j] W_shared[i,j,k]
// out[c,b] = sum_i v_b[i] * u[c,i],  u[c,i] = sum_{m,k} W_last[c,i,m,k]
//
// Fast path: fp16 MFMA GEMM  bik[m=b*64+t][i*64+k] = A[m,:] . Bt[i*64+k,:]
// 256x256 tile, BK=64, 8 waves (2M x 4N). Round-7: phase-skewed reads (each
// quadrant's ds_reads issue one phase before its MFMA; LDS latency hides under
// the barrier), counted vmcnt with >=1-phase lead, per-XCD 8x8 supertiles.

typedef _Float16 f16;
typedef __attribute__((ext_vector_type(8))) _Float16 f16x8;
typedef __attribute__((ext_vector_type(2))) _Float16 f16x2;
typedef __attribute__((ext_vector_type(4))) float f32x4;

#define GLDS16(g, l)                                                      \
    __builtin_amdgcn_global_load_lds(                                     \
        (const __attribute__((address_space(1))) void*)(g),               \
        (__attribute__((address_space(3))) void*)(l), 16, 0, 0)

#define BARRIER() asm volatile("s_barrier" ::: "memory")
#define VMCNT(n) asm volatile("s_waitcnt vmcnt(" #n ")" ::: "memory")

// ---------------- K1: u[c,i] = sum over 4096 contiguous floats ----------------
__global__ __launch_bounds__(256) void k_usum(const float* __restrict__ Wl,
                                              float* __restrict__ u) {
    int ci = blockIdx.x;  // c*64 + i
    const float4* p = (const float4*)(Wl + (size_t)ci * 4096);
    int tid = threadIdx.x;
    float s = 0.f;
#pragma unroll
    for (int q = 0; q < 4; ++q) {
        float4 v = p[tid + 256 * q];
        s += v.x + v.y + v.z + v.w;
    }
    __shared__ float red[256];
    red[tid] = s;
    __syncthreads();
    if (tid < 128) red[tid] += red[tid + 128];
    __syncthreads();
    if (tid < 64) {
        float x = red[tid] + red[tid + 64];
#pragma unroll
        for (int off = 32; off > 0; off >>= 1) x += __shfl_down(x, off, 64);
        if (tid == 0) u[ci] = x;
    }
}

// ---------------- convert A: fp32 -> fp16, layout preserved -------------------
__global__ __launch_bounds__(256) void k_cvtA(const float* __restrict__ in,
                                              f16* __restrict__ out) {
    int idx = blockIdx.x * 256 + threadIdx.x;  // handles 8 floats
    const float4* p = (const float4*)in + (size_t)idx * 2;
    float4 v0 = p[0], v1 = p[1];
    f16x8 h;
    h[0] = (f16)v0.x; h[1] = (f16)v0.y; h[2] = (f16)v0.z; h[3] = (f16)v0.w;
    h[4] = (f16)v1.x; h[5] = (f16)v1.y; h[6] = (f16)v1.z; h[7] = (f16)v1.w;
    *(f16x8*)(out + (size_t)idx * 8) = h;
}

// ------------- convert W: [i,j,k] fp32 -> Bt[i*64+k][j] fp16 ------------------
__global__ __launch_bounds__(256) void k_cvtW(const float* __restrict__ W,
                                              f16* __restrict__ Bt) {
    int o = blockIdx.x * 256 + threadIdx.x;  // 0..1048575, handles 2 j's
    int col = o >> 8;                        // i*64+k
    int j = (o & 255) << 1;
    int i = col >> 6, k = col & 63;
    const float* src = W + ((size_t)i * 512 + j) * 64 + k;
    f16x2 pk;
    pk[0] = (f16)src[0];
    pk[1] = (f16)src[64];
    *(f16x2*)(Bt + (size_t)col * 512 + j) = pk;
}

// =============== 256x256 MFMA GEMM, phase-skewed reads ========================
// LDS (dynamic 128 KB): buf q in {0,1} at q*65536; slots within buf:
//   A0 +0, A1 +16384, B0 +32768, B1 +49152   (each 128 rows x 64 f16 = 16 KB)
// Swizzle invariant: LDS[(r<<7) + s*16] holds global 16B-slot (s ^ (r&7)).
//
// Steady kt (phases end with BARRIER; MFMA operands were read pre-barrier):
//  P0: RD b1@kt       ; STAGE A0,B0@kt+1 ; MFMA q0(a0,b0) ; VMCNT(4)  [A1@kt]
//  P1: RD a1@kt       ;                    MFMA q1(a0,b1)
//  P2:                  STAGE B1,A1@kt+1 ; MFMA q2(a1,b0) ; VMCNT(4)  [A0,B0@kt+1]
//  P3: RD a0,b0@kt+1  ;                    MFMA q3(a1,b1) ; VMCNT(2)  [B1@kt+1]
// Per-wave vmcnt queue verified: every wait has >=1 phase lead; every cross-
// wave DMA->ds_read crossing is vmcnt-before-barrier protected; every slot
// overwrite is >=2 barriers after its last reader's lgkm-complete use.

#define STAGE_A(qq, ha, ktv) do {                                             \
    _Pragma("unroll") for (int u_ = 0; u_ < 2; ++u_) {                        \
        int idx_ = (wid * 2 + u_) * 64 + lane;                                \
        int r_ = idx_ >> 3;                                                   \
        int ls_ = (idx_ & 7) ^ (r_ & 7);                                      \
        const f16* g_ = A + (size_t)(m0 + (ha) * 128 + r_) * 512              \
                          + (ktv) * 64 + ls_ * 8;                             \
        char* l_ = smem + (qq) * 65536 + (ha) * 16384 + (wid * 2 + u_) * 1024;\
        GLDS16(g_, l_);                                                       \
    } } while (0)

#define STAGE_B(qq, hb, ktv) do {                                             \
    _Pragma("unroll") for (int u_ = 0; u_ < 2; ++u_) {                        \
        int idx_ = (wid * 2 + u_) * 64 + lane;                                \
        int r_ = idx_ >> 3;                                                   \
        int ls_ = (idx_ & 7) ^ (r_ & 7);                                      \
        const f16* g_ = Bt + (size_t)(n0 + (hb) * 128 + r_) * 512             \
                           + (ktv) * 64 + ls_ * 8;                            \
        char* l_ = smem + (qq) * 65536 + 32768 + (hb) * 16384                 \
                        + (wid * 2 + u_) * 1024;                              \
        GLDS16(g_, l_);                                                       \
    } } while (0)

#define RD_A(ha, ktv, areg) do {                                              \
    _Pragma("unroll") for (int mf_ = 0; mf_ < 4; ++mf_)                       \
    _Pragma("unroll") for (int kq_ = 0; kq_ < 2; ++kq_) {                     \
        int ra_ = wr * 64 + mf_ * 16 + (lane & 15);                           \
        int off_ = ((ra_ << 7) + kq_ * 64 + ((lane >> 4) << 4))               \
                   ^ ((ra_ & 7) << 4);                                        \
        areg[mf_][kq_] = *(const f16x8*)(smem + ((ktv) & 1) * 65536           \
                                         + (ha) * 16384 + off_);              \
    } } while (0)

#define RD_B(hb, ktv, breg) do {                                              \
    _Pragma("unroll") for (int nf_ = 0; nf_ < 2; ++nf_)                       \
    _Pragma("unroll") for (int kq_ = 0; kq_ < 2; ++kq_) {                     \
        int rb_ = wc * 32 + nf_ * 16 + (lane & 15);                           \
        int off_ = ((rb_ << 7) + kq_ * 64 + ((lane >> 4) << 4))               \
                   ^ ((rb_ & 7) << 4);                                        \
        breg[nf_][kq_] = *(const f16x8*)(smem + ((ktv) & 1) * 65536           \
                                         + 32768 + (hb) * 16384 + off_);      \
    } } while (0)

#define MFMA_Q(qa_, qb_, areg, breg) do {                                     \
    __builtin_amdgcn_s_setprio(1);                                            \
    _Pragma("unroll") for (int mf_ = 0; mf_ < 4; ++mf_)                       \
    _Pragma("unroll") for (int nf_ = 0; nf_ < 2; ++nf_)                       \
    _Pragma("unroll") for (int kq_ = 0; kq_ < 2; ++kq_)                       \
        acc[qa_][qb_][mf_][nf_] = __builtin_amdgcn_mfma_f32_16x16x32_f16(     \
            areg[mf_][kq_], breg[nf_][kq_], acc[qa_][qb_][mf_][nf_], 0, 0, 0);\
    __builtin_amdgcn_s_setprio(0);                                            \
    } while (0)

__global__ __launch_bounds__(512) void k_gemm_256(const f16* __restrict__ A,
                                                  const f16* __restrict__ Bt,
                                                  __half* __restrict__ outp) {
    extern __shared__ char smem[];
    const int tid = threadIdx.x;
    const int lane = tid & 63;
    const int wid = tid >> 6;
    // Per-XCD 8x8 supertiles: XCD x (= lin&7 under RR dispatch) owns 4
    // supertiles; each supertile = 8 m-blocks x 8 n-blocks -> 4MB A + 4MB B
    // working set = one XCD L2. Bijective: (x, q>>6) -> st, q&63 -> position.
    int lin = blockIdx.x;
    int x = lin & 7, q = lin >> 3;
    int st = 4 * x + (q >> 6);
    int sub = q & 63;
    const int m0 = ((st >> 1) * 8 + (sub >> 3)) * 256;  // 16 st-rows * 8 = 128 m-blocks
    const int n0 = ((st & 1) * 8 + (sub & 7)) * 256;    // 2 st-cols * 8 = 16 n-blocks
    const int wr = wid >> 2, wc = wid & 3;  // 2M x 4N waves

    f32x4 acc[2][2][4][2];
#pragma unroll
    for (int xx = 0; xx < 2; ++xx)
#pragma unroll
        for (int yy = 0; yy < 2; ++yy)
#pragma unroll
            for (int zz = 0; zz < 4; ++zz)
#pragma unroll
                for (int ww = 0; ww < 2; ++ww) acc[xx][yy][zz][ww] = (f32x4)0.f;

    f16x8 a0[4][2], a1[4][2], b0[2][2], b1[2][2];

    // ---- prologue: stage kt0 fully + A0,B0@1; read a0,b0@0 ----
    STAGE_A(0, 0, 0);
    STAGE_B(0, 0, 0);
    STAGE_B(0, 1, 0);
    STAGE_A(0, 1, 0);
    STAGE_A(1, 0, 1);
    STAGE_B(1, 0, 1);
    VMCNT(8);            // A0@0, B0@0 complete
    BARRIER();
    RD_A(0, 0, a0);
    RD_B(0, 0, b0);
    VMCNT(4);            // B1@0, A1@0 complete (leaves A0@1, B0@1)
    BARRIER();

    // ---- kt = 0 (A0/B0@1 already staged in prologue) ----
    RD_B(1, 0, b1);
    MFMA_Q(0, 0, a0, b0);
    BARRIER();
    RD_A(1, 0, a1);
    MFMA_Q(0, 1, a0, b1);
    BARRIER();
    STAGE_B(1, 1, 1);
    STAGE_A(1, 1, 1);
    MFMA_Q(1, 0, a1, b0);
    VMCNT(4);            // A0@1, B0@1 complete
    BARRIER();
    RD_A(0, 1, a0);
    RD_B(0, 1, b0);
    MFMA_Q(1, 1, a1, b1);
    VMCNT(2);            // B1@1 complete
    BARRIER();

    // ---- steady kt = 1..6 ----
#pragma unroll
    for (int kt = 1; kt < 7; ++kt) {
        // P0
        RD_B(1, kt, b1);
        STAGE_A((kt + 1) & 1, 0, kt + 1);
        STAGE_B((kt + 1) & 1, 0, kt + 1);
        MFMA_Q(0, 0, a0, b0);
        VMCNT(4);        // A1@kt complete
        BARRIER();
        // P1
        RD_A(1, kt, a1);
        MFMA_Q(0, 1, a0, b1);
        BARRIER();
        // P2
        STAGE_B((kt + 1) & 1, 1, kt + 1);
        STAGE_A((kt + 1) & 1, 1, kt + 1);
        MFMA_Q(1, 0, a1, b0);
        VMCNT(4);        // A0@kt+1, B0@kt+1 complete
        BARRIER();
        // P3
        RD_A(0, kt + 1, a0);
        RD_B(0, kt + 1, b0);
        MFMA_Q(1, 1, a1, b1);
        VMCNT(2);        // B1@kt+1 complete
        BARRIER();
    }

    // ---- kt = 7 (no staging) ----
    RD_B(1, 7, b1);
    MFMA_Q(0, 0, a0, b0);
    VMCNT(0);            // A1@7 complete
    BARRIER();
    RD_A(1, 7, a1);
    MFMA_Q(0, 1, a0, b1);
    BARRIER();
    MFMA_Q(1, 0, a1, b0);
    BARRIER();
    MFMA_Q(1, 1, a1, b1);
    BARRIER();

    // epilogue: stage 256x256 fp16 C tile in LDS (exactly 128 KB), coalesced out
    __half* Cs = (__half*)smem;
#pragma unroll
    for (int qa = 0; qa < 2; ++qa)
#pragma unroll
        for (int qb = 0; qb < 2; ++qb)
#pragma unroll
            for (int mf = 0; mf < 4; ++mf)
#pragma unroll
                for (int nf = 0; nf < 2; ++nf)
#pragma unroll
                    for (int j = 0; j < 4; ++j) {
                        int row = qa * 128 + wr * 64 + mf * 16 + ((lane >> 4) << 2) + j;
                        int col = qb * 128 + wc * 32 + nf * 16 + (lane & 15);
                        Cs[row * 256 + col] = __float2half(acc[qa][qb][mf][nf][j]);
                    }
    BARRIER();
#pragma unroll
    for (int it = 0; it < 16; ++it) {
        int idx = it * 512 + tid;
        int r = idx >> 5, seg = idx & 31;
        *(float4*)(outp + (size_t)(m0 + r) * 4096 + n0 + seg * 8) =
            *(const float4*)(Cs + r * 256 + seg * 8);
    }
}

// --------- legacy fp32 GEMM (fallback when ws too small for fp16 path) --------
#define BM 128
#define BN 64
#define BK 32
__global__ __launch_bounds__(256) void k_gemm(const float* __restrict__ A,
                                              const float* __restrict__ W,
                                              __half* __restrict__ out,
                                              int a_off, int a_stride) {
    __shared__ float As[BK * BM];
    __shared__ float Bs[BK * BN];
    int i0 = blockIdx.x;
    int m0 = blockIdx.y * BM;
    int tid = threadIdx.x;
    int tx = tid & 15, ty = tid >> 4;
    float acc[8][4];
#pragma unroll
    for (int q = 0; q < 8; ++q)
#pragma unroll
        for (int c = 0; c < 4; ++c) acc[q][c] = 0.f;
    const float* wbase = W + (size_t)i0 * 32768;
    for (int j0 = 0; j0 < 512; j0 += BK) {
        {
            int c4 = tid & 7;
            int r = tid >> 3;
#pragma unroll
            for (int p = 0; p < 4; ++p) {
                int row = r + 32 * p;
                float4 v = *(const float4*)(A + (size_t)a_off +
                                            (size_t)(m0 + row) * a_stride + j0 + 4 * c4);
                As[(4 * c4 + 0) * BM + row] = v.x;
                As[(4 * c4 + 1) * BM + row] = v.y;
                As[(4 * c4 + 2) * BM + row] = v.z;
                As[(4 * c4 + 3) * BM + row] = v.w;
            }
            const float4* src = (const float4*)(wbase + (size_t)j0 * 64);
            float4* dst = (float4*)Bs;
            dst[tid] = src[tid];
            dst[tid + 256] = src[tid + 256];
        }
        __syncthreads();
#pragma unroll
        for (int kk = 0; kk < BK; ++kk) {
            float bv[4], av[8];
#pragma unroll
            for (int c = 0; c < 4; ++c) bv[c] = Bs[kk * BN + 4 * tx + c];
#pragma unroll
            for (int q = 0; q < 8; ++q) av[q] = As[kk * BM + 8 * ty + q];
#pragma unroll
            for (int q = 0; q < 8; ++q)
#pragma unroll
                for (int c = 0; c < 4; ++c) acc[q][c] += av[q] * bv[c];
        }
        __syncthreads();
    }
#pragma unroll
    for (int q = 0; q < 8; ++q) {
        int m = m0 + 8 * ty + q;
        __half* o = out + (size_t)m * 4096 + i0 * 64 + 4 * tx;
#pragma unroll
        for (int c = 0; c < 4; ++c) o[c] = __float2half(acc[q][c]);
    }
}

// ---------- scan: v_b <- v_b @ M_b(t), t=0..63, + fused out[c,b] --------------
__global__ __launch_bounds__(256) void k_scan(const __half* __restrict__ bik,
                                              const float* __restrict__ u,
                                              float* __restrict__ out) {
    int b = blockIdx.x;
    int tid = threadIdx.x;
    int k = tid & 63, grp = tid >> 6;
    __shared__ float vsh[64];
    __shared__ float part[256];
    if (tid < 64) vsh[tid] = 1.0f;
    const __half* base = bik + (size_t)b * 64 * 4096 + grp * 16 * 64 + k;
    __half bufA[16], bufB[16];
#pragma unroll
    for (int q = 0; q < 16; ++q) bufA[q] = base[q * 64];  // t = 0
    __syncthreads();
    for (int t = 0; t < 64; t += 2) {
        {   // even step: compute with bufA, prefetch t+1 into bufB
            const __half* pn = base + (size_t)(t + 1) * 4096;
#pragma unroll
            for (int q = 0; q < 16; ++q) bufB[q] = pn[q * 64];
            float s = 0.f;
#pragma unroll
            for (int q = 0; q < 16; ++q) s += vsh[grp * 16 + q] * __half2float(bufA[q]);
            part[tid] = s;
            __syncthreads();
            if (tid < 64) vsh[k] = part[k] + part[64 + k] + part[128 + k] + part[192 + k];
            __syncthreads();
        }
        {   // odd step: compute with bufB, prefetch t+2 into bufA (clamped)
            int t2 = (t + 2 < 64) ? (t + 2) : 63;
            const __half* pn = base + (size_t)t2 * 4096;
#pragma unroll
            for (int q = 0; q < 16; ++q) bufA[q] = pn[q * 64];
            float s = 0.f;
#pragma unroll
            for (int q = 0; q < 16; ++q) s += vsh[grp * 16 + q] * __half2float(bufB[q]);
            part[tid] = s;
            __syncthreads();
            if (tid < 64) vsh[k] = part[k] + part[64 + k] + part[128 + k] + part[192 + k];
            __syncthreads();
        }
    }
    // fused epilogue: out[c, b] = sum_i u[c,i] * v[i]
    if (tid < 100) {
        const float* uc = u + tid * 64;
        float s = 0.f;
#pragma unroll 8
        for (int i = 0; i < 64; ++i) s += uc[i] * vsh[i];
        out[tid * 512 + b] = s;
    }
}

// ---------------- fallback per-t update --------------------------------------
__global__ __launch_bounds__(256) void k_update(const __half* __restrict__ Mt,
                                                const float* __restrict__ vin,
                                                float* __restrict__ vout, int first) {
    int o = blockIdx.x * 256 + threadIdx.x;
    int b = o >> 6, k = o & 63;
    const __half* m = Mt + (size_t)b * 4096;
    float s = 0.f;
    if (first) {
#pragma unroll 8
        for (int i = 0; i < 64; ++i) s += __half2float(m[i * 64 + k]);
    } else {
        const float* v = vin + (size_t)b * 64;
#pragma unroll 8
        for (int i = 0; i < 64; ++i) s += v[i] * __half2float(m[i * 64 + k]);
    }
    vout[o] = s;
}

// ---------------- out[c,b] = sum_i u[c,i] * v[b,i] (fallback path) ------------
__global__ __launch_bounds__(256) void k_final(const float* __restrict__ u,
                                               const float* __restrict__ v,
                                               float* __restrict__ out) {
    int o = blockIdx.x * 256 + threadIdx.x;  // c*512 + b
    int c = o >> 9, b = o & 511;
    const float* uc = u + c * 64;
    const float* vb = v + (size_t)b * 64;
    float s = 0.f;
#pragma unroll 8
    for (int i = 0; i < 64; ++i) s += uc[i] * vb[i];
    out[o] = s;
}

extern "C" void kernel_launch(void* const* d_in, const int* in_sizes, int n_in,
                              void* d_out, int out_size, void* d_ws, size_t ws_size,
                              hipStream_t stream) {
    const float* tensor = (const float*)d_in[0];
    const float* Wsh = (const float*)d_in[1];
    const float* Wl = (const float*)d_in[2];
    float* out = (float*)d_out;
    char* ws = (char*)d_ws;

    const size_t bik_bytes = (size_t)32768 * 4096 * sizeof(__half);  // 256 MB
    const size_t fast_bytes = bik_bytes + (512u << 10) + ((size_t)16777216 * 2) + ((size_t)4096 * 512 * 2);

    if (ws_size >= fast_bytes) {
        // ---- fp16 MFMA path ----
        __half* bik = (__half*)ws;
        float* u = (float*)(ws + bik_bytes);
        f16* Af16 = (f16*)(ws + bik_bytes + (512u << 10));
        f16* Btw = Af16 + (size_t)16777216;

        k_cvtA<<<8192, 256, 0, stream>>>(tensor, Af16);
        k_cvtW<<<4096, 256, 0, stream>>>(Wsh, Btw);
        k_usum<<<6400, 256, 0, stream>>>(Wl, u);
        (void)hipFuncSetAttribute((const void*)k_gemm_256,
                                  hipFuncAttributeMaxDynamicSharedMemorySize, 131072);
        k_gemm_256<<<2048, 512, 131072, stream>>>(Af16, Btw, bik);
        k_scan<<<512, 256, 0, stream>>>(bik, u, out);
    } else if (ws_size >= bik_bytes + (2u << 20)) {
        // ---- fp32 big path ----
        __half* bik = (__half*)ws;
        float* u = (float*)(ws + bik_bytes);

        k_usum<<<6400, 256, 0, stream>>>(Wl, u);
        dim3 g(64, 256);
        k_gemm<<<g, 256, 0, stream>>>(tensor, Wsh, bik, 0, 512);
        k_scan<<<512, 256, 0, stream>>>(bik, u, out);
    } else {
        // ---- per-t fallback ----
        __half* bikt = (__half*)ws;
        float* u = (float*)(ws + (size_t)(4 << 20));
        float* v0 = (float*)(ws + (size_t)(4 << 20) + (64 << 10));
        float* v1 = v0 + 32768;

        k_usum<<<6400, 256, 0, stream>>>(Wl, u);
        for (int t = 0; t < 64; ++t) {
            dim3 g(64, 4);
            k_gemm<<<g, 256, 0, stream>>>(tensor, Wsh, bikt, t * 512, 32768);
            float* vin = (t & 1) ? v0 : v1;
            float* vout = (t & 1) ? v1 : v0;
            k_update<<<128, 256, 0, stream>>>(bikt, (t == 0) ? v0 : vin, vout, t == 0);
        }
        k_final<<<200, 256, 0, stream>>>(u, v1, out);
    }
}

// Round 9
// 265.617 us; speedup vs baseline: 1.5856x; 1.5856x over previous
//
#include <hip/hip_runtime.h>
#include <hip/hip_fp16.h>

// tensor  [B=512, T=64, N=512] f32 ; W_shared[R=64, N=512, R=64] f32
// W_last  [C=100, R=64, M=64, R=64] f32 ; out [C=100, B=512] f32
//
// v_b (len 64): v <- v @ M_b(t),  M_b(t)[i,k] = sum_j x[b,t,j] W_shared[i,j,k]
// out[c,b] = sum_i v_b[i] * u[c,i],  u[c,i] = sum_{m,k} W_last[c,i,m,k]
//
// Round 9 = round 8 with the NT-store type fixed (ext_vector f32x4, not
// HIP_vector_type float4): GEMM = round-6 schedule + non-temporal C stores;
// scan = global_load_lds double-buffered staging; cvtA/cvtW/usum fused.

typedef _Float16 f16;
typedef __attribute__((ext_vector_type(8))) _Float16 f16x8;
typedef __attribute__((ext_vector_type(2))) _Float16 f16x2;
typedef __attribute__((ext_vector_type(4))) float f32x4;

#define GLDS16(g, l)                                                      \
    __builtin_amdgcn_global_load_lds(                                     \
        (const __attribute__((address_space(1))) void*)(g),               \
        (__attribute__((address_space(3))) void*)(l), 16, 0, 0)

#define BARRIER() asm volatile("s_barrier" ::: "memory")
#define VMCNT(n) asm volatile("s_waitcnt vmcnt(" #n ")" ::: "memory")

// ---------------- standalone usum (fallback paths) ----------------------------
__global__ __launch_bounds__(256) void k_usum(const float* __restrict__ Wl,
                                              float* __restrict__ u) {
    int ci = blockIdx.x;  // c*64 + i
    const float4* p = (const float4*)(Wl + (size_t)ci * 4096);
    int tid = threadIdx.x;
    float s = 0.f;
#pragma unroll
    for (int q = 0; q < 4; ++q) {
        float4 v = p[tid + 256 * q];
        s += v.x + v.y + v.z + v.w;
    }
    __shared__ float red[256];
    red[tid] = s;
    __syncthreads();
    if (tid < 128) red[tid] += red[tid + 128];
    __syncthreads();
    if (tid < 64) {
        float x = red[tid] + red[tid + 64];
#pragma unroll
        for (int off = 32; off > 0; off >>= 1) x += __shfl_down(x, off, 64);
        if (tid == 0) u[ci] = x;
    }
}

// ------- fused prep: cvtA (blocks 0..8191), cvtW (8192..12287), usum (rest) ---
__global__ __launch_bounds__(256) void k_prep(const float* __restrict__ tensor,
                                              const float* __restrict__ Wsh,
                                              const float* __restrict__ Wl,
                                              f16* __restrict__ Af16,
                                              f16* __restrict__ Btw,
                                              float* __restrict__ u) {
    __shared__ float red[256];
    int blk = blockIdx.x;
    int tid = threadIdx.x;
    if (blk < 8192) {
        // cvtA: fp32 -> fp16, layout preserved (8 floats/thread)
        int idx = blk * 256 + tid;
        const float4* p = (const float4*)tensor + (size_t)idx * 2;
        float4 v0 = p[0], v1 = p[1];
        f16x8 h;
        h[0] = (f16)v0.x; h[1] = (f16)v0.y; h[2] = (f16)v0.z; h[3] = (f16)v0.w;
        h[4] = (f16)v1.x; h[5] = (f16)v1.y; h[6] = (f16)v1.z; h[7] = (f16)v1.w;
        *(f16x8*)(Af16 + (size_t)idx * 8) = h;
    } else if (blk < 12288) {
        // cvtW: W[i,j,k] fp32 -> Bt[i*64+k][j] fp16 (2 j's/thread)
        int o = (blk - 8192) * 256 + tid;
        int col = o >> 8;
        int j = (o & 255) << 1;
        int i = col >> 6, k = col & 63;
        const float* src = Wsh + ((size_t)i * 512 + j) * 64 + k;
        f16x2 pk;
        pk[0] = (f16)src[0];
        pk[1] = (f16)src[64];
        *(f16x2*)(Btw + (size_t)col * 512 + j) = pk;
    } else {
        // usum: u[c,i] = sum over 4096 contiguous floats
        int ci = blk - 12288;
        const float4* p = (const float4*)(Wl + (size_t)ci * 4096);
        float s = 0.f;
#pragma unroll
        for (int q = 0; q < 4; ++q) {
            float4 v = p[tid + 256 * q];
            s += v.x + v.y + v.z + v.w;
        }
        red[tid] = s;
        __syncthreads();
        if (tid < 128) red[tid] += red[tid + 128];
        __syncthreads();
        if (tid < 64) {
            float x = red[tid] + red[tid + 64];
#pragma unroll
            for (int off = 32; off > 0; off >>= 1) x += __shfl_down(x, off, 64);
            if (tid == 0) u[ci] = x;
        }
    }
}

// =============== 256x256 MFMA GEMM, 4-barrier/1-vmcnt K-tiles =================
// (round-6 schedule, twice-validated; epilogue stores are non-temporal)
// LDS (dynamic 128 KB): buf q in {0,1} at q*65536; slots within buf:
//   A0 +0, A1 +16384, B0 +32768, B1 +49152   (each 128 rows x 64 f16 = 16 KB)
// Swizzle invariant: LDS[(r<<7) + s*16] holds global 16B-slot (s ^ (r&7)).

#define STAGE_A(qq, ha, ktv) do {                                             \
    _Pragma("unroll") for (int u_ = 0; u_ < 2; ++u_) {                        \
        int idx_ = (wid * 2 + u_) * 64 + lane;                                \
        int r_ = idx_ >> 3;                                                   \
        int ls_ = (idx_ & 7) ^ (r_ & 7);                                      \
        const f16* g_ = A + (size_t)(m0 + (ha) * 128 + r_) * 512              \
                          + (ktv) * 64 + ls_ * 8;                             \
        char* l_ = smem + (qq) * 65536 + (ha) * 16384 + (wid * 2 + u_) * 1024;\
        GLDS16(g_, l_);                                                       \
    } } while (0)

#define STAGE_B(qq, hb, ktv) do {                                             \
    _Pragma("unroll") for (int u_ = 0; u_ < 2; ++u_) {                        \
        int idx_ = (wid * 2 + u_) * 64 + lane;                                \
        int r_ = idx_ >> 3;                                                   \
        int ls_ = (idx_ & 7) ^ (r_ & 7);                                      \
        const f16* g_ = Bt + (size_t)(n0 + (hb) * 128 + r_) * 512             \
                           + (ktv) * 64 + ls_ * 8;                            \
        char* l_ = smem + (qq) * 65536 + 32768 + (hb) * 16384                 \
                        + (wid * 2 + u_) * 1024;                              \
        GLDS16(g_, l_);                                                       \
    } } while (0)

#define RD_A(ha, ktv) do {                                                    \
    _Pragma("unroll") for (int mf_ = 0; mf_ < 4; ++mf_)                       \
    _Pragma("unroll") for (int kq_ = 0; kq_ < 2; ++kq_) {                     \
        int ra_ = wr * 64 + mf_ * 16 + (lane & 15);                           \
        int off_ = ((ra_ << 7) + kq_ * 64 + ((lane >> 4) << 4))               \
                   ^ ((ra_ & 7) << 4);                                        \
        a[mf_][kq_] = *(const f16x8*)(smem + ((ktv) & 1) * 65536              \
                                      + (ha) * 16384 + off_);                 \
    } } while (0)

#define RD_B(hb, ktv, breg) do {                                              \
    _Pragma("unroll") for (int nf_ = 0; nf_ < 2; ++nf_)                       \
    _Pragma("unroll") for (int kq_ = 0; kq_ < 2; ++kq_) {                     \
        int rb_ = wc * 32 + nf_ * 16 + (lane & 15);                           \
        int off_ = ((rb_ << 7) + kq_ * 64 + ((lane >> 4) << 4))               \
                   ^ ((rb_ & 7) << 4);                                        \
        breg[nf_][kq_] = *(const f16x8*)(smem + ((ktv) & 1) * 65536           \
                                         + 32768 + (hb) * 16384 + off_);      \
    } } while (0)

#define MFMA_Q(qa_, qb_, breg) do {                                           \
    __builtin_amdgcn_s_setprio(1);                                            \
    _Pragma("unroll") for (int mf_ = 0; mf_ < 4; ++mf_)                       \
    _Pragma("unroll") for (int nf_ = 0; nf_ < 2; ++nf_)                       \
    _Pragma("unroll") for (int kq_ = 0; kq_ < 2; ++kq_)                       \
        acc[qa_][qb_][mf_][nf_] = __builtin_amdgcn_mfma_f32_16x16x32_f16(     \
            a[mf_][kq_], breg[nf_][kq_], acc[qa_][qb_][mf_][nf_], 0, 0, 0);   \
    __builtin_amdgcn_s_setprio(0);                                            \
    } while (0)

__global__ __launch_bounds__(512) void k_gemm_256(const f16* __restrict__ A,
                                                  const f16* __restrict__ Bt,
                                                  __half* __restrict__ outp) {
    extern __shared__ char smem[];
    const int tid = threadIdx.x;
    const int lane = tid & 63;
    const int wid = tid >> 6;
    // XCD-aware swizzle (nwg=2048, 2048%8==0 -> simple form is bijective)
    int lin = blockIdx.x;
    int swz = (lin & 7) * 256 + (lin >> 3);
    const int n0 = (swz & 15) * 256;   // 16 n-blocks
    const int m0 = (swz >> 4) * 256;   // 128 m-blocks
    const int wr = wid >> 2, wc = wid & 3;  // 2M x 4N waves

    f32x4 acc[2][2][4][2];
#pragma unroll
    for (int x = 0; x < 2; ++x)
#pragma unroll
        for (int y = 0; y < 2; ++y)
#pragma unroll
            for (int z = 0; z < 4; ++z)
#pragma unroll
                for (int w = 0; w < 2; ++w) acc[x][y][z][w] = (f32x4)0.f;

    f16x8 a[4][2], b0[2][2], b1[2][2];

    // prologue: kt0 all four (A0,B0,B1,A1), kt1 three (A0,B0,B1)
    STAGE_A(0, 0, 0);
    STAGE_B(0, 0, 0);
    STAGE_B(0, 1, 0);
    STAGE_A(0, 1, 0);
    STAGE_A(1, 0, 1);
    STAGE_B(1, 0, 1);
    STAGE_B(1, 1, 1);

    for (int kt = 0; kt < 6; ++kt) {
        VMCNT(6);                            // kt's 4 half-tiles complete
        BARRIER();                           // ...and visible to all waves
        // ph0
        RD_A(0, kt);
        RD_B(0, kt, b0);
        STAGE_A((kt + 1) & 1, 1, kt + 1);    // A1@kt+1 (dead since ph2 kt-1)
        MFMA_Q(0, 0, b0);
        BARRIER();
        // ph1
        RD_B(1, kt, b1);
        MFMA_Q(0, 1, b1);
        BARRIER();
        // ph2
        RD_A(1, kt);
        STAGE_A(kt & 1, 0, kt + 2);          // A0@kt+2 (dead since ph0)
        STAGE_B(kt & 1, 0, kt + 2);          // B0@kt+2 (dead since ph0)
        MFMA_Q(1, 0, b0);
        BARRIER();
        // ph3
        STAGE_B(kt & 1, 1, kt + 2);          // B1@kt+2 (dead since ph1)
        MFMA_Q(1, 1, b1);
        BARRIER();
    }
    {   // ---- kt = 6 (no kt+2 stages) ----
        VMCNT(6);
        BARRIER();
        RD_A(0, 6);
        RD_B(0, 6, b0);
        STAGE_A(1, 1, 7);                    // A1@7
        MFMA_Q(0, 0, b0);
        BARRIER();
        RD_B(1, 6, b1);
        MFMA_Q(0, 1, b1);
        BARRIER();
        RD_A(1, 6);
        MFMA_Q(1, 0, b0);
        BARRIER();
        MFMA_Q(1, 1, b1);
        BARRIER();
    }
    {   // ---- kt = 7 (no stages) ----
        VMCNT(0);
        BARRIER();
        RD_A(0, 7);
        RD_B(0, 7, b0);
        MFMA_Q(0, 0, b0);
        BARRIER();
        RD_B(1, 7, b1);
        MFMA_Q(0, 1, b1);
        BARRIER();
        RD_A(1, 7);
        MFMA_Q(1, 0, b0);
        BARRIER();
        MFMA_Q(1, 1, b1);
        BARRIER();
    }

    // epilogue: stage 256x256 fp16 C tile in LDS, then NON-TEMPORAL stores
    // (C is 256 MB streaming -> bypass L2/L3 so A/Bt stay cache-resident)
    __half* Cs = (__half*)smem;
#pragma unroll
    for (int qa = 0; qa < 2; ++qa)
#pragma unroll
        for (int qb = 0; qb < 2; ++qb)
#pragma unroll
            for (int mf = 0; mf < 4; ++mf)
#pragma unroll
                for (int nf = 0; nf < 2; ++nf)
#pragma unroll
                    for (int j = 0; j < 4; ++j) {
                        int row = qa * 128 + wr * 64 + mf * 16 + ((lane >> 4) << 2) + j;
                        int col = qb * 128 + wc * 32 + nf * 16 + (lane & 15);
                        Cs[row * 256 + col] = __float2half(acc[qa][qb][mf][nf][j]);
                    }
    BARRIER();
#pragma unroll
    for (int it = 0; it < 16; ++it) {
        int idx = it * 512 + tid;
        int r = idx >> 5, seg = idx & 31;
        __builtin_nontemporal_store(
            *(const f32x4*)(Cs + r * 256 + seg * 8),
            (f32x4*)(outp + (size_t)(m0 + r) * 4096 + n0 + seg * 8));
    }
}

// --------- legacy fp32 GEMM (fallback when ws too small for fp16 path) --------
#define BM 128
#define BN 64
#define BK 32
__global__ __launch_bounds__(256) void k_gemm(const float* __restrict__ A,
                                              const float* __restrict__ W,
                                              __half* __restrict__ out,
                                              int a_off, int a_stride) {
    __shared__ float As[BK * BM];
    __shared__ float Bs[BK * BN];
    int i0 = blockIdx.x;
    int m0 = blockIdx.y * BM;
    int tid = threadIdx.x;
    int tx = tid & 15, ty = tid >> 4;
    float acc[8][4];
#pragma unroll
    for (int q = 0; q < 8; ++q)
#pragma unroll
        for (int c = 0; c < 4; ++c) acc[q][c] = 0.f;
    const float* wbase = W + (size_t)i0 * 32768;
    for (int j0 = 0; j0 < 512; j0 += BK) {
        {
            int c4 = tid & 7;
            int r = tid >> 3;
#pragma unroll
            for (int p = 0; p < 4; ++p) {
                int row = r + 32 * p;
                float4 v = *(const float4*)(A + (size_t)a_off +
                                            (size_t)(m0 + row) * a_stride + j0 + 4 * c4);
                As[(4 * c4 + 0) * BM + row] = v.x;
                As[(4 * c4 + 1) * BM + row] = v.y;
                As[(4 * c4 + 2) * BM + row] = v.z;
                As[(4 * c4 + 3) * BM + row] = v.w;
            }
            const float4* src = (const float4*)(wbase + (size_t)j0 * 64);
            float4* dst = (float4*)Bs;
            dst[tid] = src[tid];
            dst[tid + 256] = src[tid + 256];
        }
        __syncthreads();
#pragma unroll
        for (int kk = 0; kk < BK; ++kk) {
            float bv[4], av[8];
#pragma unroll
            for (int c = 0; c < 4; ++c) bv[c] = Bs[kk * BN + 4 * tx + c];
#pragma unroll
            for (int q = 0; q < 8; ++q) av[q] = As[kk * BM + 8 * ty + q];
#pragma unroll
            for (int q = 0; q < 8; ++q)
#pragma unroll
                for (int c = 0; c < 4; ++c) acc[q][c] += av[q] * bv[c];
        }
        __syncthreads();
    }
#pragma unroll
    for (int q = 0; q < 8; ++q) {
        int m = m0 + 8 * ty + q;
        __half* o = out + (size_t)m * 4096 + i0 * 64 + 4 * tx;
#pragma unroll
        for (int c = 0; c < 4; ++c) o[c] = __float2half(acc[q][c]);
    }
}

// ---------- scan: v_b <- v_b @ M_b(t), t=0..63, + fused out[c,b] --------------
// M_t (8 KB) staged into LDS via global_load_lds (1 KB/wave-instr), double-
// buffered. Choreography per t: VMCNT(0) [my stage(t) done] -> barrier
// [everyone's stage(t) visible AND everyone past iter t-1's reads of the
// other buf] -> issue STAGE(t+1) into other buf -> compute t from buf[t&1].
__global__ __launch_bounds__(256) void k_scan(const __half* __restrict__ bik,
                                              const float* __restrict__ u,
                                              float* __restrict__ out) {
    __shared__ char sm[2][8192];
    __shared__ float vsh[64];
    __shared__ float part[256];
    int b = blockIdx.x;
    int tid = threadIdx.x;
    int k = tid & 63, grp = tid >> 6;
    const int lane = tid & 63;
    const int wid = tid >> 6;
    if (tid < 64) vsh[tid] = 1.0f;
    const char* base = (const char*)(bik + (size_t)b * 64 * 4096);

    // stage t = 0 into buf 0 (2 GLDS16 per thread-wave-slot)
#pragma unroll
    for (int u_ = 0; u_ < 2; ++u_) {
        const char* g = base + (wid * 2 + u_) * 1024 + lane * 16;
        GLDS16(g, &sm[0][0] + (wid * 2 + u_) * 1024);
    }

    for (int t = 0; t < 64; ++t) {
        VMCNT(0);          // my part of stage(t) complete
        __syncthreads();   // all parts visible; all past iter t-1's reads
        if (t < 63) {
            const char* gb = base + (size_t)(t + 1) * 8192;
#pragma unroll
            for (int u_ = 0; u_ < 2; ++u_) {
                const char* g = gb + (wid * 2 + u_) * 1024 + lane * 16;
                GLDS16(g, &sm[(t + 1) & 1][0] + (wid * 2 + u_) * 1024);
            }
        }
        const __half* Mt = (const __half*)&sm[t & 1][0];
        float s = 0.f;
#pragma unroll
        for (int q = 0; q < 16; ++q) {
            int i = grp * 16 + q;
            s += vsh[i] * __half2float(Mt[i * 64 + k]);
        }
        part[tid] = s;
        __syncthreads();
        if (tid < 64) vsh[k] = part[k] + part[64 + k] + part[128 + k] + part[192 + k];
        __syncthreads();
    }
    // fused epilogue: out[c, b] = sum_i u[c,i] * v[i]
    if (tid < 100) {
        const float* uc = u + tid * 64;
        float s = 0.f;
#pragma unroll 8
        for (int i = 0; i < 64; ++i) s += uc[i] * vsh[i];
        out[tid * 512 + b] = s;
    }
}

// ---------------- fallback per-t update --------------------------------------
__global__ __launch_bounds__(256) void k_update(const __half* __restrict__ Mt,
                                                const float* __restrict__ vin,
                                                float* __restrict__ vout, int first) {
    int o = blockIdx.x * 256 + threadIdx.x;
    int b = o >> 6, k = o & 63;
    const __half* m = Mt + (size_t)b * 4096;
    float s = 0.f;
    if (first) {
#pragma unroll 8
        for (int i = 0; i < 64; ++i) s += __half2float(m[i * 64 + k]);
    } else {
        const float* v = vin + (size_t)b * 64;
#pragma unroll 8
        for (int i = 0; i < 64; ++i) s += v[i] * __half2float(m[i * 64 + k]);
    }
    vout[o] = s;
}

// ---------------- out[c,b] = sum_i u[c,i] * v[b,i] (fallback path) ------------
__global__ __launch_bounds__(256) void k_final(const float* __restrict__ u,
                                               const float* __restrict__ v,
                                               float* __restrict__ out) {
    int o = blockIdx.x * 256 + threadIdx.x;  // c*512 + b
    int c = o >> 9, b = o & 511;
    const float* uc = u + c * 64;
    const float* vb = v + (size_t)b * 64;
    float s = 0.f;
#pragma unroll 8
    for (int i = 0; i < 64; ++i) s += uc[i] * vb[i];
    out[o] = s;
}

extern "C" void kernel_launch(void* const* d_in, const int* in_sizes, int n_in,
                              void* d_out, int out_size, void* d_ws, size_t ws_size,
                              hipStream_t stream) {
    const float* tensor = (const float*)d_in[0];
    const float* Wsh = (const float*)d_in[1];
    const float* Wl = (const float*)d_in[2];
    float* out = (float*)d_out;
    char* ws = (char*)d_ws;

    const size_t bik_bytes = (size_t)32768 * 4096 * sizeof(__half);  // 256 MB
    const size_t fast_bytes = bik_bytes + (512u << 10) + ((size_t)16777216 * 2) + ((size_t)4096 * 512 * 2);

    if (ws_size >= fast_bytes) {
        // ---- fp16 MFMA path ----
        __half* bik = (__half*)ws;
        float* u = (float*)(ws + bik_bytes);
        f16* Af16 = (f16*)(ws + bik_bytes + (512u << 10));
        f16* Btw = Af16 + (size_t)16777216;

        k_prep<<<18688, 256, 0, stream>>>(tensor, Wsh, Wl, Af16, Btw, u);
        (void)hipFuncSetAttribute((const void*)k_gemm_256,
                                  hipFuncAttributeMaxDynamicSharedMemorySize, 131072);
        k_gemm_256<<<2048, 512, 131072, stream>>>(Af16, Btw, bik);
        k_scan<<<512, 256, 0, stream>>>(bik, u, out);
    } else if (ws_size >= bik_bytes + (2u << 20)) {
        // ---- fp32 big path ----
        __half* bik = (__half*)ws;
        float* u = (float*)(ws + bik_bytes);

        k_usum<<<6400, 256, 0, stream>>>(Wl, u);
        dim3 g(64, 256);
        k_gemm<<<g, 256, 0, stream>>>(tensor, Wsh, bik, 0, 512);
        k_scan<<<512, 256, 0, stream>>>(bik, u, out);
    } else {
        // ---- per-t fallback ----
        __half* bikt = (__half*)ws;
        float* u = (float*)(ws + (size_t)(4 << 20));
        float* v0 = (float*)(ws + (size_t)(4 << 20) + (64 << 10));
        float* v1 = v0 + 32768;

        k_usum<<<6400, 256, 0, stream>>>(Wl, u);
        for (int t = 0; t < 64; ++t) {
            dim3 g(64, 4);
            k_gemm<<<g, 256, 0, stream>>>(tensor, Wsh, bikt, t * 512, 32768);
            float* vin = (t & 1) ? v0 : v1;
            float* vout = (t & 1) ? v1 : v0;
            k_update<<<128, 256, 0, stream>>>(bikt, (t == 0) ? v0 : vin, vout, t == 0);
        }
        k_final<<<200, 256, 0, stream>>>(u, v1, out);
    }
}